// Round 9
// baseline (86.342 us; speedup 1.0000x reference)
//
#include <hip/hip_runtime.h>

typedef float f2 __attribute__((ext_vector_type(2)));
typedef float f4 __attribute__((ext_vector_type(4)));
typedef _Float16 h2t __attribute__((ext_vector_type(2)));

constexpr int Hh = 224, Ww = 224, Bb = 8, Kc = 4, RAD = 5;

// 256 threads = 32x8; each thread owns 2 vertically-adjacent pixels -> 32x16 tile.
// SYMMETRY: w_ij == w_ji -> only FORWARD taps (dy>0, or dy==0 && dx>0); per center
// S0 = sum_fwd w, S1[k] = sum_fwd w*p_j[k]; then
//   num[k] = sum_i p_i[k]*(2*S1_i[k] + p_i[k]),  den[k] = sum_i (p_i[k]*(S0_i+1) + S1_i[k])
// (diagonal w_ii = 1 exact).
// ROLLED row loop (unroll 2): static body ~3 KB instead of ~11 KB straight-line --
// attacks cold-I-cache front-end stalls (the fixed ~19 us in main that survived the
// occupancy-null R6, LDS-null R7, and instruction-halving-null R8 experiments).
// Row/center/pair-group activity is encoded branch-free via row constants that are
// either DSC*dy^2 or -1e30 (exp2 -> exactly 0), keeping slot code straight-line.
constexpr int TX = 32;
constexpr int TILEH = 16;
constexpr int NTHR = 256;
constexpr int SW = TX + 2 * RAD;      // 42
constexpr int SH = TILEH + RAD;       // 21 (bottom halo only; forward taps never look up)
constexpr int SSTR = SW + 1;          // 43 (odd; col 42 = pad column)
constexpr int GXD = Ww / TX;          // 7
constexpr int GYD = Hh / TILEH;       // 14
constexpr int PB = GXD * GYD;         // 98 blocks per batch image

constexpr float LOG2E = 1.44269504f;
constexpr float KI = -0.01f * LOG2E;         // intensity coeff (pre-scaled for exp2)
constexpr float DSC = -0.0625f * LOG2E;      // dist coeff     (pre-scaled for exp2)
// column d^2, index = dx+5 (dx in [-5,6]); D2[11]=1e5 -> base ~ -9000 -> exp2 == 0,
// masking the dx=+6 slot that the 2-wide pair structure over-covers.
constexpr float D2[12] = {25.f,16.f,9.f,4.f,1.f,0.f,1.f,4.f,9.f,16.f,25.f,1e5f};

static __device__ inline f4 splat4(float x) { return (f4){x, x, x, x}; }

// f16 labels packed INSIDE f32-typed LDS vectors: loads are ds_read_b128 by
// construction (cannot degrade to ds_read_u16); unpack is pure VALU.
static __device__ inline float pack2(float a, float b) {
    return __builtin_bit_cast(float, __builtin_amdgcn_cvt_pkrtz(a, b));
}
static __device__ inline f4 unpack4(float y, float z) {
    const h2t a = __builtin_bit_cast(h2t, y);
    const h2t b = __builtin_bit_cast(h2t, z);
    return (f4){(float)a.x, (float)a.y, (float)b.x, (float)b.y};
}

__global__ __launch_bounds__(NTHR, 3) void ncut_main(const float* __restrict__ images,
                                                     const float* __restrict__ labels,
                                                     float* __restrict__ acc) {
    // fused tap record: {img*255 (f32), labels k0,k1 (f16x2), labels k2,k3 (f16x2), pad}
    __shared__ f4 stap[SH * SSTR];               // 21*43*16 = 14.4 KB
    __shared__ float red[4][8];

    const int b   = blockIdx.z;
    const int x0  = blockIdx.x * TX;
    const int y0  = blockIdx.y * TILEH;
    const int tid = threadIdx.x;

    const float* imgb = images + (size_t)b * (Hh * Ww);
    const float* labb = labels + (size_t)b * (Kc * Hh * Ww);

    // Stage tile + bottom/side halo (incl. stride-pad column as OOB).
    // OOB: img = 1e19 -> weight underflows to exactly 0; labels = 0.
    for (int idx = tid; idx < SH * SSTR; idx += NTHR) {
        const int lx = idx % SSTR, ly = idx / SSTR;
        const int gx = x0 - RAD + lx, gy = y0 + ly;    // no top halo
        float iv = 1e19f, p01 = 0.f, p23 = 0.f;
        if (lx < SW && gx >= 0 && gx < Ww && gy < Hh) {
            const int g = gy * Ww + gx;
            iv  = imgb[g] * 255.0f;
            p01 = pack2(labb[g], labb[Hh * Ww + g]);
            p23 = pack2(labb[2 * Hh * Ww + g], labb[3 * Hh * Ww + g]);
        }
        stap[idx] = (f4){iv, p01, p23, 0.f};
    }
    __syncthreads();

    const int tx = tid & 31;
    const int ty = tid >> 5;      // 0..7
    const int r0 = 2 * ty;        // tile rows r0, r0+1 (LDS row == tile row)

    const f4 crec0 = stap[r0 * SSTR + tx + RAD];
    const f4 crec1 = stap[(r0 + 1) * SSTR + tx + RAD];
    const float c0 = crec0.x;
    const float c1 = crec1.x;

    f4 s1a = splat4(0.f), s1b = splat4(0.f);     // S1 per center (f4 over classes)
    f2 s0a = (f2){0.f, 0.f}, s0b = (f2){0.f, 0.f};

    // LDS row r0+dr: center0 sees dy=dr (active 0..5; dy==0 needs dx>0 -> pairs i>=3),
    //                center1 sees dy=dr-1 (active 1..6; dy==0 at dr==1 -> pairs i>=3).
    // Inactive combos get row constant -1e30 -> exp2 == 0 -> contribute exactly nothing.
#pragma unroll 2
    for (int dr = 0; dr < 7; ++dr) {
        const int rowoff = (r0 + dr) * SSTR + tx;
        const float fd0 = (float)dr;
        const float fd1 = fd0 - 1.f;
        const float g0  = (dr <= 5) ? DSC * fd0 * fd0 : -1e30f;   // center0, pairs i>=3
        const float g0l = (dr >= 1) ? g0 : -1e30f;                // center0, pairs i<3
        const float g1  = (dr >= 1) ? DSC * fd1 * fd1 : -1e30f;   // center1, pairs i>=3
        const float g1l = (dr >= 2) ? g1 : -1e30f;                // center1, pairs i<3
#pragma unroll
        for (int i = 0; i < 6; ++i) {
            const f4 rA = stap[rowoff + 2 * i];
            const f4 rB = stap[rowoff + 2 * i + 1];
            const f2 v  = (f2){rA.x, rB.x};
            const f4 pa = unpack4(rA.y, rA.z);
            const f4 pb = unpack4(rB.y, rB.z);
            const f2 dcol = (f2){D2[2 * i] * DSC, D2[2 * i + 1] * DSC};
            const float ga = (i < 3) ? g0l : g0;
            const float gb = (i < 3) ? g1l : g1;
            {   // center 0
                const f2 dd = v - c0;
                const f2 a = __builtin_elementwise_fma(dd * KI, dd, dcol + ga);
                const float e0 = __builtin_amdgcn_exp2f(a.x);
                const float e1 = __builtin_amdgcn_exp2f(a.y);
                s0a += (f2){e0, e1};
                s1a = __builtin_elementwise_fma(splat4(e0), pa, s1a);
                s1a = __builtin_elementwise_fma(splat4(e1), pb, s1a);
            }
            {   // center 1
                const f2 dd = v - c1;
                const f2 a = __builtin_elementwise_fma(dd * KI, dd, dcol + gb);
                const float e0 = __builtin_amdgcn_exp2f(a.x);
                const float e1 = __builtin_amdgcn_exp2f(a.y);
                s0b += (f2){e0, e1};
                s1b = __builtin_elementwise_fma(splat4(e0), pa, s1b);
                s1b = __builtin_elementwise_fma(splat4(e1), pb, s1b);
            }
        }
    }

    // fold symmetric + diagonal contributions for this thread's 2 pixels
    const f4 p0 = unpack4(crec0.y, crec0.z);
    const f4 p1 = unpack4(crec1.y, crec1.z);
    const float S0a = s0a.x + s0a.y;
    const float S0b = s0b.x + s0b.y;

    const f4 numv = p0 * (splat4(2.f) * s1a + p0) + p1 * (splat4(2.f) * s1b + p1);
    const f4 denv = p0 * splat4(S0a + 1.f) + s1a + p1 * splat4(S0b + 1.f) + s1b;

    float vals[8] = {numv.x, numv.y, numv.z, numv.w, denv.x, denv.y, denv.z, denv.w};

#pragma unroll
    for (int i = 0; i < 8; ++i) {
        float vv = vals[i];
#pragma unroll
        for (int off = 32; off > 0; off >>= 1) vv += __shfl_down(vv, off, 64);
        vals[i] = vv;
    }

    const int wave = tid >> 6, lane = tid & 63;   // 4 waves
    if (lane == 0) {
#pragma unroll
        for (int i = 0; i < 8; ++i) red[wave][i] = vals[i];
    }
    __syncthreads();

    if (tid < 8) {
        const int gid = blockIdx.x + GXD * blockIdx.y + GXD * GYD * blockIdx.z;
        acc[gid * 8 + tid] = red[0][tid] + red[1][tid] + red[2][tid] + red[3][tid];
    }
}

__global__ void ncut_final(const float* __restrict__ acc, float* __restrict__ out) {
    __shared__ float red[4][64];
    const int t = threadIdx.x;           // 0..255
    const int combo = t & 63;
    const int chunk = t >> 6;            // 0..3
    const int k = combo & 3, b = (combo >> 2) & 7;
    const int part = combo >> 5;         // 0 = num, 1 = den
    float s = 0.f;
    for (int j = chunk; j < PB; j += 4)
        s += acc[(b * PB + j) * 8 + k + 4 * part];
    red[chunk][combo] = s;
    __syncthreads();
    if (t < 64) {
        float v = red[0][t] + red[1][t] + red[2][t] + red[3][t];
        const float den = __shfl(v, (t + 32) & 63, 64);
        float r = (t < 32) ? fabsf(v / den) : 0.f;
#pragma unroll
        for (int off = 32; off > 0; off >>= 1) r += __shfl_down(r, off, 64);
        if (t == 0) out[0] = (float)Kc - r * (1.0f / (float)Bb);
    }
}

extern "C" void kernel_launch(void* const* d_in, const int* in_sizes, int n_in,
                              void* d_out, int out_size, void* d_ws, size_t ws_size,
                              hipStream_t stream) {
    const float* images = (const float*)d_in[0];
    const float* labels = (const float*)d_in[1];
    float* out = (float*)d_out;
    float* acc = (float*)d_ws;  // PB*Bb blocks * 8 partials, fully overwritten each launch

    dim3 grid(GXD, GYD, Bb);    // 7 x 14 x 8
    ncut_main<<<grid, NTHR, 0, stream>>>(images, labels, acc);
    ncut_final<<<1, 256, 0, stream>>>(acc, out);
}

// Round 10
// 83.488 us; speedup vs baseline: 1.0342x; 1.0342x over previous
//
#include <hip/hip_runtime.h>

typedef float f2 __attribute__((ext_vector_type(2)));
typedef float f4 __attribute__((ext_vector_type(4)));
typedef _Float16 h2t __attribute__((ext_vector_type(2)));

constexpr int Hh = 224, Ww = 224, Bb = 8, Kc = 4, RAD = 5;

// 256 threads = 32x8; each thread owns 2 vertically-adjacent pixels -> 32x16 tile.
// SYMMETRY: w_ij == w_ji, so only FORWARD taps (dy>0, or dy==0 && dx>0) are computed;
// per center: S0 = sum_fwd w, S1[k] = sum_fwd w*p_j[k]. Global sums then use
//   num[k] = sum_i p_i[k]*(2*S1_i[k] + p_i[k]),  den[k] = sum_i (p_i[k]*(S0_i+1) + S1_i[k])
// (diagonal w_ii = 1 exactly). Halves every instruction class vs the full window,
// and removes the top halo (staging 26 -> 21 rows).
constexpr int TX = 32;
constexpr int TILEH = 16;
constexpr int NTHR = 256;
constexpr int SW = TX + 2 * RAD;      // 42
constexpr int SH = TILEH + RAD;       // 21 (bottom halo only; forward taps never look up)
constexpr int SSTR = SW + 1;          // 43 (odd; col 42 = pad column)
constexpr int GXD = Ww / TX;          // 7
constexpr int GYD = Hh / TILEH;       // 14
constexpr int PB = GXD * GYD;         // 98 blocks per batch image

constexpr float LOG2E = 1.44269504f;
constexpr float KI = -0.01f * LOG2E;         // intensity coeff (pre-scaled for exp2)
constexpr float DSC = -0.0625f * LOG2E;      // dist coeff     (pre-scaled for exp2)
// column d^2, index = dx+5 (dx in [-5,6]); D2[11]=1e5 -> exp2 underflows to exactly 0,
// masking the dx=+6 slot that the 2-wide pair structure over-covers.
constexpr float D2[12] = {25.f,16.f,9.f,4.f,1.f,0.f,1.f,4.f,9.f,16.f,25.f,1e5f};
// row d^2 for forward dy = 0..5
constexpr float DR2[6] = {0.f,1.f,4.f,9.f,16.f,25.f};

static __device__ inline f4 splat4(float x) { return (f4){x, x, x, x}; }

// f16 labels packed INSIDE f32-typed LDS vectors: loads are ds_read_b128 by
// construction (cannot degrade to ds_read_u16); unpack is pure VALU.
static __device__ inline float pack2(float a, float b) {
    return __builtin_bit_cast(float, __builtin_amdgcn_cvt_pkrtz(a, b));
}
static __device__ inline f4 unpack4(float y, float z) {
    const h2t a = __builtin_bit_cast(h2t, y);
    const h2t b = __builtin_bit_cast(h2t, z);
    return (f4){(float)a.x, (float)a.y, (float)b.x, (float)b.y};
}

__global__ __launch_bounds__(NTHR, 3) void ncut_main(const float* __restrict__ images,
                                                     const float* __restrict__ labels,
                                                     float* __restrict__ acc) {
    // fused tap record: {img*255 (f32), labels k0,k1 (f16x2), labels k2,k3 (f16x2), pad}
    __shared__ f4 stap[SH * SSTR];               // 21*43*16 = 14.4 KB
    __shared__ float red[4][8];

    const int b   = blockIdx.z;
    const int x0  = blockIdx.x * TX;
    const int y0  = blockIdx.y * TILEH;
    const int tid = threadIdx.x;

    const float* imgb = images + (size_t)b * (Hh * Ww);
    const float* labb = labels + (size_t)b * (Kc * Hh * Ww);

    // Stage tile + bottom/side halo (incl. stride-pad column as OOB).
    // OOB: img = 1e19 -> weight underflows to exactly 0; labels = 0.
    for (int idx = tid; idx < SH * SSTR; idx += NTHR) {
        const int lx = idx % SSTR, ly = idx / SSTR;
        const int gx = x0 - RAD + lx, gy = y0 + ly;    // no top halo
        float iv = 1e19f, p01 = 0.f, p23 = 0.f;
        if (lx < SW && gx >= 0 && gx < Ww && gy < Hh) {
            const int g = gy * Ww + gx;
            iv  = imgb[g] * 255.0f;
            p01 = pack2(labb[g], labb[Hh * Ww + g]);
            p23 = pack2(labb[2 * Hh * Ww + g], labb[3 * Hh * Ww + g]);
        }
        stap[idx] = (f4){iv, p01, p23, 0.f};
    }
    __syncthreads();

    const int tx = tid & 31;
    const int ty = tid >> 5;      // 0..7
    const int r0 = 2 * ty;        // tile rows r0, r0+1 (LDS row == tile row)

    const f4 crec0 = stap[r0 * SSTR + tx + RAD];
    const f4 crec1 = stap[(r0 + 1) * SSTR + tx + RAD];
    const float c0 = crec0.x;
    const float c1 = crec1.x;

    f4 s1a = splat4(0.f), s1b = splat4(0.f);     // S1 per center (f4 over classes)
    f2 s0a = (f2){0.f, 0.f}, s0b = (f2){0.f, 0.f};

    // LDS row r0+dr serves center0 with dy=dr (active dr 0..5; dr==0 needs dx>0)
    // and center1 with dy=dr-1 (active dr 1..6; dr==1 needs dx>0). All guards are
    // compile-time after full unroll; dy==0 rows run pairs i>=3 only (dx 1..6, 6 masked).
#pragma unroll
    for (int dr = 0; dr < 7; ++dr) {
        const int rowoff = (r0 + dr) * SSTR + tx;
#pragma unroll
        for (int i = 0; i < 6; ++i) {
            const bool act0 = (dr <= 5) && (dr >= 1 || i >= 3);
            const bool act1 = (dr >= 1) && (dr >= 2 || i >= 3);
            if (act0 || act1) {
                const f4 rA = stap[rowoff + 2 * i];
                const f4 rB = stap[rowoff + 2 * i + 1];
                const f2 v  = (f2){rA.x, rB.x};
                const f4 pa = unpack4(rA.y, rA.z);
                const f4 pb = unpack4(rB.y, rB.z);
                if (act0) {
                    const f2 base = (f2){(D2[2 * i] + DR2[dr]) * DSC,
                                         (D2[2 * i + 1] + DR2[dr]) * DSC};
                    const f2 dd = v - c0;
                    const f2 a = __builtin_elementwise_fma(dd * KI, dd, base);
                    const float e0 = __builtin_amdgcn_exp2f(a.x);
                    const float e1 = __builtin_amdgcn_exp2f(a.y);
                    s0a += (f2){e0, e1};
                    s1a = __builtin_elementwise_fma(splat4(e0), pa, s1a);
                    s1a = __builtin_elementwise_fma(splat4(e1), pb, s1a);
                }
                if (act1) {
                    const f2 base = (f2){(D2[2 * i] + DR2[dr - 1]) * DSC,
                                         (D2[2 * i + 1] + DR2[dr - 1]) * DSC};
                    const f2 dd = v - c1;
                    const f2 a = __builtin_elementwise_fma(dd * KI, dd, base);
                    const float e0 = __builtin_amdgcn_exp2f(a.x);
                    const float e1 = __builtin_amdgcn_exp2f(a.y);
                    s0b += (f2){e0, e1};
                    s1b = __builtin_elementwise_fma(splat4(e0), pa, s1b);
                    s1b = __builtin_elementwise_fma(splat4(e1), pb, s1b);
                }
            }
        }
    }

    // fold symmetric + diagonal contributions for this thread's 2 pixels
    const f4 p0 = unpack4(crec0.y, crec0.z);
    const f4 p1 = unpack4(crec1.y, crec1.z);
    const float S0a = s0a.x + s0a.y;
    const float S0b = s0b.x + s0b.y;

    const f4 numv = p0 * (splat4(2.f) * s1a + p0) + p1 * (splat4(2.f) * s1b + p1);
    const f4 denv = p0 * splat4(S0a + 1.f) + s1a + p1 * splat4(S0b + 1.f) + s1b;

    float vals[8] = {numv.x, numv.y, numv.z, numv.w, denv.x, denv.y, denv.z, denv.w};

#pragma unroll
    for (int i = 0; i < 8; ++i) {
        float vv = vals[i];
#pragma unroll
        for (int off = 32; off > 0; off >>= 1) vv += __shfl_down(vv, off, 64);
        vals[i] = vv;
    }

    const int wave = tid >> 6, lane = tid & 63;   // 4 waves
    if (lane == 0) {
#pragma unroll
        for (int i = 0; i < 8; ++i) red[wave][i] = vals[i];
    }
    __syncthreads();

    if (tid < 8) {
        const int gid = blockIdx.x + GXD * blockIdx.y + GXD * GYD * blockIdx.z;
        acc[gid * 8 + tid] = red[0][tid] + red[1][tid] + red[2][tid] + red[3][tid];
    }
}

__global__ void ncut_final(const float* __restrict__ acc, float* __restrict__ out) {
    __shared__ float red[4][64];
    const int t = threadIdx.x;           // 0..255
    const int combo = t & 63;
    const int chunk = t >> 6;            // 0..3
    const int k = combo & 3, b = (combo >> 2) & 7;
    const int part = combo >> 5;         // 0 = num, 1 = den
    float s = 0.f;
    for (int j = chunk; j < PB; j += 4)
        s += acc[(b * PB + j) * 8 + k + 4 * part];
    red[chunk][combo] = s;
    __syncthreads();
    if (t < 64) {
        float v = red[0][t] + red[1][t] + red[2][t] + red[3][t];
        const float den = __shfl(v, (t + 32) & 63, 64);
        float r = (t < 32) ? fabsf(v / den) : 0.f;
#pragma unroll
        for (int off = 32; off > 0; off >>= 1) r += __shfl_down(r, off, 64);
        if (t == 0) out[0] = (float)Kc - r * (1.0f / (float)Bb);
    }
}

extern "C" void kernel_launch(void* const* d_in, const int* in_sizes, int n_in,
                              void* d_out, int out_size, void* d_ws, size_t ws_size,
                              hipStream_t stream) {
    const float* images = (const float*)d_in[0];
    const float* labels = (const float*)d_in[1];
    float* out = (float*)d_out;
    float* acc = (float*)d_ws;  // PB*Bb blocks * 8 partials, fully overwritten each launch

    dim3 grid(GXD, GYD, Bb);    // 7 x 14 x 8
    ncut_main<<<grid, NTHR, 0, stream>>>(images, labels, acc);
    ncut_final<<<1, 256, 0, stream>>>(acc, out);
}